// Round 7
// baseline (463.094 us; speedup 1.0000x reference)
//
#include <hip/hip_runtime.h>

// ---------------------------------------------------------------------------
// In2MA: windowed dual attention. B=4, C=64, H=W=256, WIN=8, HEADS=8, INNER=64
// 4096 windows of 64 tokens x 64 ch. One 256-thread block per window.
// R9 = R8 (spill-proof 50176 B pool) + two changes:
//  1) __launch_bounds__(256,3): request 3 blocks/CU (total-reg cap 170;
//     R8 body peaks ~60 live -> no spill risk). R7 evidence: (256,3) was the
//     only run showing ~3-block occupancy. R8's (256,2) let the allocator
//     fill a 2-waves/EU budget, blocking the 3rd block.
//  2) S5 k1c/v1_color reads vectorized to float4 (512 ds_read_b32 -> 128
//     ds_read_b128 per path; bases 16B-aligned).
// Column map of the 64x196 fp32 pool:
//   [0:64)   x -> v1 -> out1 -> final
//   [64:96)  pan -> q1c -> out_color -> x_v2(lo) -> out2(lo)
//   [96:128) k1c -> x_v2(hi) -> out2(hi)
//   [128:160) pan_k -> out_pan -> x_k2
//   [160:192) pan_q (lives until S8)
// fp32 activations in LDS + split-bf16 MFMA (hi/lo planes).
// ---------------------------------------------------------------------------

typedef __attribute__((ext_vector_type(8))) short short8;   // 8 bf16 (4 VGPRs)
typedef __attribute__((ext_vector_type(4))) float floatx4;  // MFMA accum

#define CCH  64
#define HH   256
#define WWD  256
#define HWsz (HH*WWD)
#define CHW  (CCH*HH*WWD)

#define PS   196   // pool row stride in floats (196 % 32 == 4; 196*4 % 16 == 0)
#define CV   0     // x / v1 / out1 / final
#define CQ1  64    // pan / q1c / out_color / x_v2 lo / out2 lo
#define CK1  96    // k1c / x_v2 hi / out2 hi
#define CPK  128   // pan_k / out_pan / x_k2
#define CPQ  160   // pan_q

// weight plane element offsets (hi plane at [0,WTOT), lo plane at [WTOT,2*WTOT))
#define OWPQ  0      // W_pan_q    32x32
#define OWPK  1024   // W_pan_k    32x32
#define OWV1  2048   // W_v1       64x64
#define OWV2  6144   // W_v2       64x64
#define OWK2  10240  // W_k2       32x64
#define OWQ1C 12288  // W_q1c      32x64
#define OWK1C 14336  // W_k1c      32x64
#define OWIO  16384  // W_inner_out 64x64
#define OWINT 20480  // W_inter_out 64x64
#define WTOT  24576

__device__ __forceinline__ unsigned int f2bf_u(float f) {   // RNE, value in low 16
    unsigned int u = __builtin_bit_cast(unsigned int, f);
    u += 0x7FFFu + ((u >> 16) & 1u);
    return u >> 16;
}
__device__ __forceinline__ float bfu2f(unsigned int b) {
    return __builtin_bit_cast(float, b << 16);
}

union Frag { short8 v; unsigned int u[4]; };
template <int KS> struct AF { Frag ah[KS], al[KS]; };
struct HalfF { Frag h, l; };

// Load + split-convert ONE 32-col chunk (base A, stride PS) for rows
// [m0,m0+16). MFMA 16x16x32_bf16 A layout: lane holds A[m=lane&15][k=quad*8+j].
__device__ __forceinline__ HalfF load_half(const float* __restrict__ A,
                                           int m0, int lane) {
    HalfF f;
    const int l15 = lane & 15;
    const int quad = lane >> 4;
    const float4* ap = (const float4*)(A + (m0 + l15) * PS + quad * 8);
    float4 fa = ap[0], fb = ap[1];
    float ff[8] = {fa.x, fa.y, fa.z, fa.w, fb.x, fb.y, fb.z, fb.w};
#pragma unroll
    for (int j2 = 0; j2 < 4; ++j2) {
        float f0 = ff[2 * j2], f1 = ff[2 * j2 + 1];
        unsigned int h0 = f2bf_u(f0), h1 = f2bf_u(f1);
        float r0 = f0 - bfu2f(h0), r1 = f1 - bfu2f(h1);
        f.h.u[j2] = h0 | (h1 << 16);
        f.l.u[j2] = f2bf_u(r0) | (f2bf_u(r1) << 16);
    }
    return f;
}

template <int K>
__device__ __forceinline__ AF<K / 32> load_afrag(const float* __restrict__ A,
                                                 int m0, int lane) {
    AF<K / 32> f;
#pragma unroll
    for (int kk = 0; kk < K / 32; ++kk) {
        HalfF t = load_half(A + kk * 32, m0, lane);
        f.ah[kk] = t.h; f.al[kk] = t.l;
    }
    return f;
}

// O rows [m0,m0+16), cols [0, 16*NT) (base O, stride PS) = A(16xK) @ W(NxK)^T
// split-bf16 fp32 emulation: Ah@Wh + Al@Wh + Ah@Wl (drop Al@Wl ~2^-18).
// D layout: lane holds D[row=quad*4+r][col=lane&15].
template <int K, int NT>
__device__ __forceinline__ void mm(const AF<K / 32>& f,
                                   const unsigned short* __restrict__ Wh,
                                   const unsigned short* __restrict__ Wl,
                                   float* __restrict__ O,
                                   int m0, int lane) {
    const int l15 = lane & 15;
    const int quad = lane >> 4;
#pragma unroll
    for (int nt = 0; nt < NT; ++nt) {
        floatx4 acc = {0.f, 0.f, 0.f, 0.f};
#pragma unroll
        for (int kk = 0; kk < K / 32; ++kk) {
            const int wo = (nt * 16 + l15) * K + kk * 32 + quad * 8;
            short8 bh = *(const short8*)(Wh + wo);
            short8 bl = *(const short8*)(Wl + wo);
            acc = __builtin_amdgcn_mfma_f32_16x16x32_bf16(f.ah[kk].v, bh, acc, 0, 0, 0);
            acc = __builtin_amdgcn_mfma_f32_16x16x32_bf16(f.al[kk].v, bh, acc, 0, 0, 0);
            acc = __builtin_amdgcn_mfma_f32_16x16x32_bf16(f.ah[kk].v, bl, acc, 0, 0, 0);
        }
#pragma unroll
        for (int r = 0; r < 4; ++r)
            O[(m0 + quad * 4 + r) * PS + nt * 16 + l15] = acc[r];
    }
}

// ---------------------------------------------------------------------------
// Weight fp32 -> bf16 hi/lo planes (once per launch; ws re-poisoned each call)
// ---------------------------------------------------------------------------
__global__ void cvt_w(const float* __restrict__ w0, const float* __restrict__ w1,
                      const float* __restrict__ w2, const float* __restrict__ w3,
                      const float* __restrict__ w4, const float* __restrict__ w5,
                      const float* __restrict__ w6, const float* __restrict__ w7,
                      const float* __restrict__ w8, unsigned short* __restrict__ o) {
    int i = blockIdx.x * 256 + threadIdx.x;
    const float* src; int off;
    if      (i < 1024)  { src = w0; off = 0; }
    else if (i < 2048)  { src = w1; off = 1024; }
    else if (i < 6144)  { src = w2; off = 2048; }
    else if (i < 10240) { src = w3; off = 6144; }
    else if (i < 12288) { src = w4; off = 10240; }
    else if (i < 14336) { src = w5; off = 12288; }
    else if (i < 16384) { src = w6; off = 14336; }
    else if (i < 20480) { src = w7; off = 16384; }
    else                { src = w8; off = 20480; }
    float f = src[i - off];
    unsigned int h = f2bf_u(f);
    o[i] = (unsigned short)h;
    o[WTOT + i] = (unsigned short)f2bf_u(f - bfu2f(h));
}

// ---------------------------------------------------------------------------
// Main fused kernel: one 256-thread block per window, 50176 B LDS pool.
// ---------------------------------------------------------------------------
__global__ __launch_bounds__(256, 3) void in2ma_main(
    const float* __restrict__ x, const float* __restrict__ pan,
    const float* __restrict__ posi, const float* __restrict__ posc,
    const unsigned short* __restrict__ wb, float* __restrict__ out) {
    __shared__ __align__(16) float sp[64 * PS];   // 50176 B

    const int tid  = threadIdx.x;
    const int wave = tid >> 6;   // 0..3
    const int lane = tid & 63;
    const int wid  = blockIdx.x;
    const int b    = wid >> 10;
    const int hn_i = (wid >> 5) & 31;
    const int wn_i = wid & 31;
    const int h0 = hn_i * 8, w0 = wn_i * 8;

    const float scale = 0.35355339059327373f;  // 8^-0.5 (both attentions)
    const unsigned short* wlo = wb + WTOT;
    const int s16 = wave * 16;                 // this wave's strip

    // ---- S0: stage x -> pool[0:64), pan -> pool[64:96) (fp32 transpose) ----
    {
        const int c = tid >> 2, i = tid & 3;
        const float* xp = x + (size_t)b * CHW + (size_t)c * HWsz + (size_t)h0 * WWD + w0;
#pragma unroll
        for (int r = 0; r < 2; ++r) {
            const int hl = i * 2 + r;
            const float4* p = (const float4*)(xp + hl * WWD);
            float4 a = p[0], q = p[1];
            float* d = sp + (hl * 8) * PS + CV + c;
            d[0 * PS] = a.x; d[1 * PS] = a.y; d[2 * PS] = a.z; d[3 * PS] = a.w;
            d[4 * PS] = q.x; d[5 * PS] = q.y; d[6 * PS] = q.z; d[7 * PS] = q.w;
        }
        if (tid < 128) {
            const int c2 = tid >> 2, i2 = tid & 3;
            const float* pp = pan + (size_t)b * (CHW / 2) + (size_t)c2 * HWsz
                                  + (size_t)h0 * WWD + w0;
#pragma unroll
            for (int r = 0; r < 2; ++r) {
                const int hl = i2 * 2 + r;
                const float4* p = (const float4*)(pp + hl * WWD);
                float4 a = p[0], q = p[1];
                float* d = sp + (hl * 8) * PS + CQ1 + c2;
                d[0 * PS] = a.x; d[1 * PS] = a.y; d[2 * PS] = a.z; d[3 * PS] = a.w;
                d[4 * PS] = q.x; d[5 * PS] = q.y; d[6 * PS] = q.z; d[7 * PS] = q.w;
            }
        }
    }
    __syncthreads();

    // ---- Phase A: wave s owns strip s; A-fragments to regs once, outputs
    // written in place / to own strip. No barriers inside.
    {
        AF<2> fx = load_afrag<64>(sp + CV,  s16, lane);   // x strip -> regs
        AF<1> fp = load_afrag<32>(sp + CQ1, s16, lane);   // pan strip -> regs
        mm<64, 4>(fx, wb + OWV1,  wlo + OWV1,  sp + CV,  s16, lane); // v1 over x
        mm<64, 2>(fx, wb + OWQ1C, wlo + OWQ1C, sp + CQ1, s16, lane); // q1c over pan
        mm<64, 2>(fx, wb + OWK1C, wlo + OWK1C, sp + CK1, s16, lane); // k1c
        mm<32, 2>(fp, wb + OWPQ,  wlo + OWPQ,  sp + CPQ, s16, lane); // pan_q
        mm<32, 2>(fp, wb + OWPK,  wlo + OWPK,  sp + CPK, s16, lane); // pan_k
    }
    __syncthreads();

    // ---- S3: pan MHA (8 heads, d=4, seq=64). wave: heads w, w+4; lane=token.
    // TWO-PASS softmax: no lrow[64] -> peak live ~25 regs, spill-proof at any
    // observed allocator cap. pass2 recomputes bit-identical exp; pos re-read
    // is L1-hot. Output written immediately over pan_k cols of the SAME head
    // (this wave is their only reader; DS ops in-order within a wave).
#pragma unroll
    for (int hh = 0; hh < 2; ++hh) {
        const int h = wave + hh * 4;
        const float4 qv = *(const float4*)(sp + lane * PS + CPQ + 4 * h);
        const float q0 = qv.x, q1 = qv.y, q2 = qv.z, q3 = qv.w;
        const float4* pp4 = (const float4*)(posi + h * 4096 + lane * 64);
        float sden = 0.f;
#pragma unroll
        for (int t4 = 0; t4 < 16; ++t4) {
            float4 pv = pp4[t4];
            float pvv[4] = {pv.x, pv.y, pv.z, pv.w};
#pragma unroll
            for (int u = 0; u < 4; ++u) {
                const int t = t4 * 4 + u;
                const float4 kv = *(const float4*)(sp + t * PS + CPK + 4 * h); // bcast
                float d = q0 * kv.x + q1 * kv.y + q2 * kv.z + q3 * kv.w;
                sden += __expf(d * scale + pvv[u]);
            }
        }
        const float inv = 1.f / sden;
        float o0 = 0.f, o1 = 0.f, o2 = 0.f, o3 = 0.f;
#pragma unroll
        for (int t4 = 0; t4 < 16; ++t4) {
            float4 pv = pp4[t4];
            float pvv[4] = {pv.x, pv.y, pv.z, pv.w};
#pragma unroll
            for (int u = 0; u < 4; ++u) {
                const int t = t4 * 4 + u;
                const float4 kv = *(const float4*)(sp + t * PS + CPK + 4 * h); // bcast
                float d = q0 * kv.x + q1 * kv.y + q2 * kv.z + q3 * kv.w;
                float e = __expf(d * scale + pvv[u]);
                const float4 vv = *(const float4*)(sp + t * PS + CV + 4 * h);  // v1_pan
                o0 += e * vv.x; o1 += e * vv.y; o2 += e * vv.z; o3 += e * vv.w;
            }
        }
        float4 ov; ov.x = o0 * inv; ov.y = o1 * inv; ov.z = o2 * inv; ov.w = o3 * inv;
        *(float4*)(sp + lane * PS + CPK + 4 * h) = ov;   // out_pan over pan_k[h]
    }

    // ---- S5: color MHA (seq=32 channels, d=8 token-dims). wave w: heads 2w
    // (lanes 0-31), 2w+1 (lanes 32-63); rows 8h..8h+8 == own strip. Single
    // pass (lr[32], ~50 live). k1c/v1_color rows read as float4 (16B-aligned;
    // broadcast within half-wave -> conflict-free). Output over the q1c cells
    // this same thread read (same-cell, race-free) -> cat[32:64) at CQ1.
    {
        const int h5 = wave * 2 + (lane >> 5);
        const int i5 = lane & 31;
        float q[8];
#pragma unroll
        for (int j = 0; j < 8; ++j) q[j] = sp[(8 * h5 + j) * PS + CQ1 + i5]; // q1c
        float lr[32];
#pragma unroll
        for (int j = 0; j < 8; ++j) {
            const float4* kp4 = (const float4*)(sp + (8 * h5 + j) * PS + CK1); // k1c
            const float qj = q[j];
#pragma unroll
            for (int t4 = 0; t4 < 8; ++t4) {
                float4 kv = kp4[t4];
                if (j == 0) {
                    lr[4 * t4 + 0] = qj * kv.x; lr[4 * t4 + 1] = qj * kv.y;
                    lr[4 * t4 + 2] = qj * kv.z; lr[4 * t4 + 3] = qj * kv.w;
                } else {
                    lr[4 * t4 + 0] += qj * kv.x; lr[4 * t4 + 1] += qj * kv.y;
                    lr[4 * t4 + 2] += qj * kv.z; lr[4 * t4 + 3] += qj * kv.w;
                }
            }
        }
        const float4* pp4 = (const float4*)(posc + h5 * 1024 + i5 * 32);
        float sden = 0.f;
#pragma unroll
        for (int t4 = 0; t4 < 8; ++t4) {
            float4 pv = pp4[t4];
            float pvv[4] = {pv.x, pv.y, pv.z, pv.w};
#pragma unroll
            for (int u = 0; u < 4; ++u) {
                const int t = t4 * 4 + u;
                float e = __expf(lr[t] * scale + pvv[u]);
                lr[t] = e; sden += e;
            }
        }
        const float inv = 1.f / sden;
#pragma unroll
        for (int j = 0; j < 8; ++j) {
            const float4* vp4 = (const float4*)(sp + (8 * h5 + j) * PS + CV + 32);
            float acc = 0.f;
#pragma unroll
            for (int t4 = 0; t4 < 8; ++t4) {
                float4 vv = vp4[t4];
                acc += lr[4 * t4 + 0] * vv.x + lr[4 * t4 + 1] * vv.y
                     + lr[4 * t4 + 2] * vv.z + lr[4 * t4 + 3] * vv.w;
            }
            sp[(8 * h5 + j) * PS + CQ1 + i5] = acc * inv;   // out_color over q1c
        }
    }
    __syncthreads();   // out_pan/out_color complete; v1 (CV) now dead

    // ---- Phase C: strip-local chain, no internal barriers.
    // cat = [CPK out_pan | CQ1 out_color] -> regs; out1 -> CV;
    // x_v2 = out1@Wv2^T -> CQ1 (cols 64..128, over out_color+k1c);
    // x_k2 = out1@Wk2^T -> CPK (over out_pan).
    {
        AF<2> fc;
        { HalfF a = load_half(sp + CPK, s16, lane);
          HalfF b2 = load_half(sp + CQ1, s16, lane);
          fc.ah[0] = a.h;  fc.al[0] = a.l;
          fc.ah[1] = b2.h; fc.al[1] = b2.l; }
        mm<64, 4>(fc, wb + OWIO, wlo + OWIO, sp + CV, s16, lane);   // out1
        AF<2> fo = load_afrag<64>(sp + CV, s16, lane);              // own strip
        mm<64, 4>(fo, wb + OWV2, wlo + OWV2, sp + CQ1, s16, lane);  // x_v2
        mm<64, 2>(fo, wb + OWK2, wlo + OWK2, sp + CPK, s16, lane);  // x_k2
    }
    __syncthreads();

    // ---- S8: inter attention (cosine gate), in place on x_v2.
    // thread -> (token t=lane, heads wave, wave+4).
    {
        const int t = lane;
#pragma unroll
        for (int r = 0; r < 2; ++r) {
            const int h = wave + r * 4;
            const float4 qv = *(const float4*)(sp + t * PS + CPQ + 4 * h);  // pan_q
            const float4 kv = *(const float4*)(sp + t * PS + CPK + 4 * h);  // x_k2
            float qq = qv.x * qv.x + qv.y * qv.y + qv.z * qv.z + qv.w * qv.w;
            float kk = kv.x * kv.x + kv.y * kv.y + kv.z * kv.z + kv.w * kv.w;
            float qk = qv.x * kv.x + qv.y * kv.y + qv.z * kv.z + qv.w * kv.w;
            float cosv = qk * rsqrtf(qq * kk);
            float4* vp = (float4*)(sp + t * PS + CQ1 + 8 * h);  // x_v2 -> out2
            float4 v0 = vp[0], v1 = vp[1];
            float4 r0, r1;
            r0.x = cosv * v0.x; r0.y = cosv * v0.y; r0.z = cosv * v0.z; r0.w = cosv * v0.w;
            r1.x = cosv * v1.x; r1.y = cosv * v1.y; r1.z = cosv * v1.z; r1.w = cosv * v1.w;
            vp[0] = r0; vp[1] = r1;   // same cells, same thread: race-free
        }
    }
    __syncthreads();

    // ---- S9: final = out2 @ Wint^T -> pool[0:64) (out1 dead) ----
    {
        AF<2> f9 = load_afrag<64>(sp + CQ1, s16, lane);
        mm<64, 4>(f9, wb + OWINT, wlo + OWINT, sp + CV, s16, lane);
    }
    __syncthreads();

    // ---- store: LDS transpose -> coalesced fp32 float4 stores ----
    {
        const int c = tid >> 2, i = tid & 3;
        float* op = out + (size_t)b * CHW + (size_t)c * HWsz + (size_t)h0 * WWD + w0;
#pragma unroll
        for (int r = 0; r < 2; ++r) {
            const int hl = i * 2 + r;
            float v[8];
#pragma unroll
            for (int wl = 0; wl < 8; ++wl)
                v[wl] = sp[(hl * 8 + wl) * PS + CV + c];
            float4 q0; q0.x = v[0]; q0.y = v[1]; q0.z = v[2]; q0.w = v[3];
            float4 q1; q1.x = v[4]; q1.y = v[5]; q1.z = v[6]; q1.w = v[7];
            float4* q = (float4*)(op + hl * WWD);
            q[0] = q0; q[1] = q1;
        }
    }
}

extern "C" void kernel_launch(void* const* d_in, const int* in_sizes, int n_in,
                              void* d_out, int out_size, void* d_ws, size_t ws_size,
                              hipStream_t stream) {
    (void)in_sizes; (void)n_in; (void)out_size; (void)ws_size;
    const float* x    = (const float*)d_in[0];
    const float* pan  = (const float*)d_in[1];
    const float* posi = (const float*)d_in[11];
    const float* posc = (const float*)d_in[12];
    unsigned short* wb = (unsigned short*)d_ws;  // 2*WTOT*2 = 98304 B of ws

    cvt_w<<<WTOT / 256, 256, 0, stream>>>(
        (const float*)d_in[2], (const float*)d_in[3], (const float*)d_in[4],
        (const float*)d_in[5], (const float*)d_in[6], (const float*)d_in[7],
        (const float*)d_in[8], (const float*)d_in[9], (const float*)d_in[10], wb);

    in2ma_main<<<4096, 256, 0, stream>>>(x, pan, posi, posc, wb, (float*)d_out);
}

// Round 8
// 441.642 us; speedup vs baseline: 1.0486x; 1.0486x over previous
//
#include <hip/hip_runtime.h>

// ---------------------------------------------------------------------------
// In2MA: windowed dual attention. B=4, C=64, H=W=256, WIN=8, HEADS=8, INNER=64
// 4096 windows of 64 tokens x 64 ch. One 256-thread block per window.
// R10 = R9 (50176 B pool, 3 blocks/CU) + S3 rebuilt:
//  (a) FUSED single-pass softmax: o += e*V and sden += e in one loop, divide
//      at the end (bit-identical to two-pass; the split was never needed).
//  (b) K/V held in REGISTERS (lane=token) and broadcast via v_readlane with
//      compile-time lane index: S3 LDS instructions 386 -> 6 per wave.
// Evidence: R2/R8/R9 all 365us at 8->9.6 waves/CU and +-25% VALU -> neither
// occupancy nor VALU binds; S3's ~386 uniform ds_read_b128/wave (~12cyc each
// on the shared per-CU LDS pipe) sit on every softmax iteration's critical
// path. This moves that traffic to the idle VALU pipe.
// Column map of the 64x196 fp32 pool:
//   [0:64)   x -> v1 -> out1 -> final
//   [64:96)  pan -> q1c -> out_color -> x_v2(lo) -> out2(lo)
//   [96:128) k1c -> x_v2(hi) -> out2(hi)
//   [128:160) pan_k -> out_pan -> x_k2
//   [160:192) pan_q (lives until S8)
// fp32 activations in LDS + split-bf16 MFMA (hi/lo planes).
// ---------------------------------------------------------------------------

typedef __attribute__((ext_vector_type(8))) short short8;   // 8 bf16 (4 VGPRs)
typedef __attribute__((ext_vector_type(4))) float floatx4;  // MFMA accum

#define CCH  64
#define HH   256
#define WWD  256
#define HWsz (HH*WWD)
#define CHW  (CCH*HH*WWD)

#define PS   196   // pool row stride in floats (196 % 32 == 4; 196*4 % 16 == 0)
#define CV   0     // x / v1 / out1 / final
#define CQ1  64    // pan / q1c / out_color / x_v2 lo / out2 lo
#define CK1  96    // k1c / x_v2 hi / out2 hi
#define CPK  128   // pan_k / out_pan / x_k2
#define CPQ  160   // pan_q

// weight plane element offsets (hi plane at [0,WTOT), lo plane at [WTOT,2*WTOT))
#define OWPQ  0      // W_pan_q    32x32
#define OWPK  1024   // W_pan_k    32x32
#define OWV1  2048   // W_v1       64x64
#define OWV2  6144   // W_v2       64x64
#define OWK2  10240  // W_k2       32x64
#define OWQ1C 12288  // W_q1c      32x64
#define OWK1C 14336  // W_k1c      32x64
#define OWIO  16384  // W_inner_out 64x64
#define OWINT 20480  // W_inter_out 64x64
#define WTOT  24576

__device__ __forceinline__ unsigned int f2bf_u(float f) {   // RNE, value in low 16
    unsigned int u = __builtin_bit_cast(unsigned int, f);
    u += 0x7FFFu + ((u >> 16) & 1u);
    return u >> 16;
}
__device__ __forceinline__ float bfu2f(unsigned int b) {
    return __builtin_bit_cast(float, b << 16);
}
__device__ __forceinline__ float rlf(float v, int l) {      // readlane broadcast
    return __builtin_bit_cast(float,
        __builtin_amdgcn_readlane(__builtin_bit_cast(int, v), l));
}

union Frag { short8 v; unsigned int u[4]; };
template <int KS> struct AF { Frag ah[KS], al[KS]; };
struct HalfF { Frag h, l; };

// Load + split-convert ONE 32-col chunk (base A, stride PS) for rows
// [m0,m0+16). MFMA 16x16x32_bf16 A layout: lane holds A[m=lane&15][k=quad*8+j].
__device__ __forceinline__ HalfF load_half(const float* __restrict__ A,
                                           int m0, int lane) {
    HalfF f;
    const int l15 = lane & 15;
    const int quad = lane >> 4;
    const float4* ap = (const float4*)(A + (m0 + l15) * PS + quad * 8);
    float4 fa = ap[0], fb = ap[1];
    float ff[8] = {fa.x, fa.y, fa.z, fa.w, fb.x, fb.y, fb.z, fb.w};
#pragma unroll
    for (int j2 = 0; j2 < 4; ++j2) {
        float f0 = ff[2 * j2], f1 = ff[2 * j2 + 1];
        unsigned int h0 = f2bf_u(f0), h1 = f2bf_u(f1);
        float r0 = f0 - bfu2f(h0), r1 = f1 - bfu2f(h1);
        f.h.u[j2] = h0 | (h1 << 16);
        f.l.u[j2] = f2bf_u(r0) | (f2bf_u(r1) << 16);
    }
    return f;
}

template <int K>
__device__ __forceinline__ AF<K / 32> load_afrag(const float* __restrict__ A,
                                                 int m0, int lane) {
    AF<K / 32> f;
#pragma unroll
    for (int kk = 0; kk < K / 32; ++kk) {
        HalfF t = load_half(A + kk * 32, m0, lane);
        f.ah[kk] = t.h; f.al[kk] = t.l;
    }
    return f;
}

// O rows [m0,m0+16), cols [0, 16*NT) (base O, stride PS) = A(16xK) @ W(NxK)^T
// split-bf16 fp32 emulation: Ah@Wh + Al@Wh + Ah@Wl (drop Al@Wl ~2^-18).
// D layout: lane holds D[row=quad*4+r][col=lane&15].
template <int K, int NT>
__device__ __forceinline__ void mm(const AF<K / 32>& f,
                                   const unsigned short* __restrict__ Wh,
                                   const unsigned short* __restrict__ Wl,
                                   float* __restrict__ O,
                                   int m0, int lane) {
    const int l15 = lane & 15;
    const int quad = lane >> 4;
#pragma unroll
    for (int nt = 0; nt < NT; ++nt) {
        floatx4 acc = {0.f, 0.f, 0.f, 0.f};
#pragma unroll
        for (int kk = 0; kk < K / 32; ++kk) {
            const int wo = (nt * 16 + l15) * K + kk * 32 + quad * 8;
            short8 bh = *(const short8*)(Wh + wo);
            short8 bl = *(const short8*)(Wl + wo);
            acc = __builtin_amdgcn_mfma_f32_16x16x32_bf16(f.ah[kk].v, bh, acc, 0, 0, 0);
            acc = __builtin_amdgcn_mfma_f32_16x16x32_bf16(f.al[kk].v, bh, acc, 0, 0, 0);
            acc = __builtin_amdgcn_mfma_f32_16x16x32_bf16(f.ah[kk].v, bl, acc, 0, 0, 0);
        }
#pragma unroll
        for (int r = 0; r < 4; ++r)
            O[(m0 + quad * 4 + r) * PS + nt * 16 + l15] = acc[r];
    }
}

// ---------------------------------------------------------------------------
// Weight fp32 -> bf16 hi/lo planes (once per launch; ws re-poisoned each call)
// ---------------------------------------------------------------------------
__global__ void cvt_w(const float* __restrict__ w0, const float* __restrict__ w1,
                      const float* __restrict__ w2, const float* __restrict__ w3,
                      const float* __restrict__ w4, const float* __restrict__ w5,
                      const float* __restrict__ w6, const float* __restrict__ w7,
                      const float* __restrict__ w8, unsigned short* __restrict__ o) {
    int i = blockIdx.x * 256 + threadIdx.x;
    const float* src; int off;
    if      (i < 1024)  { src = w0; off = 0; }
    else if (i < 2048)  { src = w1; off = 1024; }
    else if (i < 6144)  { src = w2; off = 2048; }
    else if (i < 10240) { src = w3; off = 6144; }
    else if (i < 12288) { src = w4; off = 10240; }
    else if (i < 14336) { src = w5; off = 12288; }
    else if (i < 16384) { src = w6; off = 14336; }
    else if (i < 20480) { src = w7; off = 16384; }
    else                { src = w8; off = 20480; }
    float f = src[i - off];
    unsigned int h = f2bf_u(f);
    o[i] = (unsigned short)h;
    o[WTOT + i] = (unsigned short)f2bf_u(f - bfu2f(h));
}

// ---------------------------------------------------------------------------
// Main fused kernel: one 256-thread block per window, 50176 B LDS pool.
// ---------------------------------------------------------------------------
__global__ __launch_bounds__(256, 3) void in2ma_main(
    const float* __restrict__ x, const float* __restrict__ pan,
    const float* __restrict__ posi, const float* __restrict__ posc,
    const unsigned short* __restrict__ wb, float* __restrict__ out) {
    __shared__ __align__(16) float sp[64 * PS];   // 50176 B

    const int tid  = threadIdx.x;
    const int wave = tid >> 6;   // 0..3
    const int lane = tid & 63;
    const int wid  = blockIdx.x;
    const int b    = wid >> 10;
    const int hn_i = (wid >> 5) & 31;
    const int wn_i = wid & 31;
    const int h0 = hn_i * 8, w0 = wn_i * 8;

    const float scale = 0.35355339059327373f;  // 8^-0.5 (both attentions)
    const unsigned short* wlo = wb + WTOT;
    const int s16 = wave * 16;                 // this wave's strip

    // ---- S0: stage x -> pool[0:64), pan -> pool[64:96) (fp32 transpose) ----
    {
        const int c = tid >> 2, i = tid & 3;
        const float* xp = x + (size_t)b * CHW + (size_t)c * HWsz + (size_t)h0 * WWD + w0;
#pragma unroll
        for (int r = 0; r < 2; ++r) {
            const int hl = i * 2 + r;
            const float4* p = (const float4*)(xp + hl * WWD);
            float4 a = p[0], q = p[1];
            float* d = sp + (hl * 8) * PS + CV + c;
            d[0 * PS] = a.x; d[1 * PS] = a.y; d[2 * PS] = a.z; d[3 * PS] = a.w;
            d[4 * PS] = q.x; d[5 * PS] = q.y; d[6 * PS] = q.z; d[7 * PS] = q.w;
        }
        if (tid < 128) {
            const int c2 = tid >> 2, i2 = tid & 3;
            const float* pp = pan + (size_t)b * (CHW / 2) + (size_t)c2 * HWsz
                                  + (size_t)h0 * WWD + w0;
#pragma unroll
            for (int r = 0; r < 2; ++r) {
                const int hl = i2 * 2 + r;
                const float4* p = (const float4*)(pp + hl * WWD);
                float4 a = p[0], q = p[1];
                float* d = sp + (hl * 8) * PS + CQ1 + c2;
                d[0 * PS] = a.x; d[1 * PS] = a.y; d[2 * PS] = a.z; d[3 * PS] = a.w;
                d[4 * PS] = q.x; d[5 * PS] = q.y; d[6 * PS] = q.z; d[7 * PS] = q.w;
            }
        }
    }
    __syncthreads();

    // ---- Phase A: wave s owns strip s; A-fragments to regs once, outputs
    // written in place / to own strip. No barriers inside.
    {
        AF<2> fx = load_afrag<64>(sp + CV,  s16, lane);   // x strip -> regs
        AF<1> fp = load_afrag<32>(sp + CQ1, s16, lane);   // pan strip -> regs
        mm<64, 4>(fx, wb + OWV1,  wlo + OWV1,  sp + CV,  s16, lane); // v1 over x
        mm<64, 2>(fx, wb + OWQ1C, wlo + OWQ1C, sp + CQ1, s16, lane); // q1c over pan
        mm<64, 2>(fx, wb + OWK1C, wlo + OWK1C, sp + CK1, s16, lane); // k1c
        mm<32, 2>(fp, wb + OWPQ,  wlo + OWPQ,  sp + CPQ, s16, lane); // pan_q
        mm<32, 2>(fp, wb + OWPK,  wlo + OWPK,  sp + CPK, s16, lane); // pan_k
    }
    __syncthreads();

    // ---- S3: pan MHA (8 heads, d=4, seq=64). wave: heads w, w+4; lane=token.
    // FUSED single pass: o += e*V and sden += e together, divide at end
    // (identical values to the two-pass version). K/V preloaded to registers
    // (lane=token, 1 b128 each) and broadcast per-t via v_readlane with a
    // compile-time lane index -> zero LDS traffic in the inner loop.
    // Output written over pan_k cols of the SAME head (this wave is their
    // only reader; K already consumed into regs).
#pragma unroll
    for (int hh = 0; hh < 2; ++hh) {
        const int h = wave + hh * 4;
        const float4 qv = *(const float4*)(sp + lane * PS + CPQ + 4 * h);
        const float q0 = qv.x, q1 = qv.y, q2 = qv.z, q3 = qv.w;
        const float4 kreg = *(const float4*)(sp + lane * PS + CPK + 4 * h); // K[lane]
        const float4 vreg = *(const float4*)(sp + lane * PS + CV  + 4 * h); // V[lane]
        const float4* pp4 = (const float4*)(posi + h * 4096 + lane * 64);
        float sden = 0.f;
        float o0 = 0.f, o1 = 0.f, o2 = 0.f, o3 = 0.f;
#pragma unroll
        for (int t4 = 0; t4 < 16; ++t4) {
            float4 pv = pp4[t4];
            float pvv[4] = {pv.x, pv.y, pv.z, pv.w};
#pragma unroll
            for (int u = 0; u < 4; ++u) {
                const int t = t4 * 4 + u;
                const float k0 = rlf(kreg.x, t), k1 = rlf(kreg.y, t);
                const float k2 = rlf(kreg.z, t), k3 = rlf(kreg.w, t);
                float d = q0 * k0 + q1 * k1 + q2 * k2 + q3 * k3;
                float e = __expf(d * scale + pvv[u]);
                sden += e;
                const float v0 = rlf(vreg.x, t), v1 = rlf(vreg.y, t);
                const float v2 = rlf(vreg.z, t), v3 = rlf(vreg.w, t);
                o0 += e * v0; o1 += e * v1; o2 += e * v2; o3 += e * v3;
            }
        }
        const float inv = 1.f / sden;
        float4 ov; ov.x = o0 * inv; ov.y = o1 * inv; ov.z = o2 * inv; ov.w = o3 * inv;
        *(float4*)(sp + lane * PS + CPK + 4 * h) = ov;   // out_pan over pan_k[h]
    }

    // ---- S5: color MHA (seq=32 channels, d=8 token-dims). wave w: heads 2w
    // (lanes 0-31), 2w+1 (lanes 32-63); rows 8h..8h+8 == own strip. Single
    // pass (lr[32], ~50 live). k1c/v1_color rows read as float4 (16B-aligned;
    // broadcast within half-wave -> conflict-free). Output over the q1c cells
    // this same thread read (same-cell, race-free) -> cat[32:64) at CQ1.
    // (readlane trick not applicable: the two half-waves process different
    // heads, but readlane broadcasts one value to the whole wave.)
    {
        const int h5 = wave * 2 + (lane >> 5);
        const int i5 = lane & 31;
        float q[8];
#pragma unroll
        for (int j = 0; j < 8; ++j) q[j] = sp[(8 * h5 + j) * PS + CQ1 + i5]; // q1c
        float lr[32];
#pragma unroll
        for (int j = 0; j < 8; ++j) {
            const float4* kp4 = (const float4*)(sp + (8 * h5 + j) * PS + CK1); // k1c
            const float qj = q[j];
#pragma unroll
            for (int t4 = 0; t4 < 8; ++t4) {
                float4 kv = kp4[t4];
                if (j == 0) {
                    lr[4 * t4 + 0] = qj * kv.x; lr[4 * t4 + 1] = qj * kv.y;
                    lr[4 * t4 + 2] = qj * kv.z; lr[4 * t4 + 3] = qj * kv.w;
                } else {
                    lr[4 * t4 + 0] += qj * kv.x; lr[4 * t4 + 1] += qj * kv.y;
                    lr[4 * t4 + 2] += qj * kv.z; lr[4 * t4 + 3] += qj * kv.w;
                }
            }
        }
        const float4* pp4 = (const float4*)(posc + h5 * 1024 + i5 * 32);
        float sden = 0.f;
#pragma unroll
        for (int t4 = 0; t4 < 8; ++t4) {
            float4 pv = pp4[t4];
            float pvv[4] = {pv.x, pv.y, pv.z, pv.w};
#pragma unroll
            for (int u = 0; u < 4; ++u) {
                const int t = t4 * 4 + u;
                float e = __expf(lr[t] * scale + pvv[u]);
                lr[t] = e; sden += e;
            }
        }
        const float inv = 1.f / sden;
#pragma unroll
        for (int j = 0; j < 8; ++j) {
            const float4* vp4 = (const float4*)(sp + (8 * h5 + j) * PS + CV + 32);
            float acc = 0.f;
#pragma unroll
            for (int t4 = 0; t4 < 8; ++t4) {
                float4 vv = vp4[t4];
                acc += lr[4 * t4 + 0] * vv.x + lr[4 * t4 + 1] * vv.y
                     + lr[4 * t4 + 2] * vv.z + lr[4 * t4 + 3] * vv.w;
            }
            sp[(8 * h5 + j) * PS + CQ1 + i5] = acc * inv;   // out_color over q1c
        }
    }
    __syncthreads();   // out_pan/out_color complete; v1 (CV) now dead

    // ---- Phase C: strip-local chain, no internal barriers.
    // cat = [CPK out_pan | CQ1 out_color] -> regs; out1 -> CV;
    // x_v2 = out1@Wv2^T -> CQ1 (cols 64..128, over out_color+k1c);
    // x_k2 = out1@Wk2^T -> CPK (over out_pan).
    {
        AF<2> fc;
        { HalfF a = load_half(sp + CPK, s16, lane);
          HalfF b2 = load_half(sp + CQ1, s16, lane);
          fc.ah[0] = a.h;  fc.al[0] = a.l;
          fc.ah[1] = b2.h; fc.al[1] = b2.l; }
        mm<64, 4>(fc, wb + OWIO, wlo + OWIO, sp + CV, s16, lane);   // out1
        AF<2> fo = load_afrag<64>(sp + CV, s16, lane);              // own strip
        mm<64, 4>(fo, wb + OWV2, wlo + OWV2, sp + CQ1, s16, lane);  // x_v2
        mm<64, 2>(fo, wb + OWK2, wlo + OWK2, sp + CPK, s16, lane);  // x_k2
    }
    __syncthreads();

    // ---- S8: inter attention (cosine gate), in place on x_v2.
    // thread -> (token t=lane, heads wave, wave+4).
    {
        const int t = lane;
#pragma unroll
        for (int r = 0; r < 2; ++r) {
            const int h = wave + r * 4;
            const float4 qv = *(const float4*)(sp + t * PS + CPQ + 4 * h);  // pan_q
            const float4 kv = *(const float4*)(sp + t * PS + CPK + 4 * h);  // x_k2
            float qq = qv.x * qv.x + qv.y * qv.y + qv.z * qv.z + qv.w * qv.w;
            float kk = kv.x * kv.x + kv.y * kv.y + kv.z * kv.z + kv.w * kv.w;
            float qk = qv.x * kv.x + qv.y * kv.y + qv.z * kv.z + qv.w * kv.w;
            float cosv = qk * rsqrtf(qq * kk);
            float4* vp = (float4*)(sp + t * PS + CQ1 + 8 * h);  // x_v2 -> out2
            float4 v0 = vp[0], v1 = vp[1];
            float4 r0, r1;
            r0.x = cosv * v0.x; r0.y = cosv * v0.y; r0.z = cosv * v0.z; r0.w = cosv * v0.w;
            r1.x = cosv * v1.x; r1.y = cosv * v1.y; r1.z = cosv * v1.z; r1.w = cosv * v1.w;
            vp[0] = r0; vp[1] = r1;   // same cells, same thread: race-free
        }
    }
    __syncthreads();

    // ---- S9: final = out2 @ Wint^T -> pool[0:64) (out1 dead) ----
    {
        AF<2> f9 = load_afrag<64>(sp + CQ1, s16, lane);
        mm<64, 4>(f9, wb + OWINT, wlo + OWINT, sp + CV, s16, lane);
    }
    __syncthreads();

    // ---- store: LDS transpose -> coalesced fp32 float4 stores ----
    {
        const int c = tid >> 2, i = tid & 3;
        float* op = out + (size_t)b * CHW + (size_t)c * HWsz + (size_t)h0 * WWD + w0;
#pragma unroll
        for (int r = 0; r < 2; ++r) {
            const int hl = i * 2 + r;
            float v[8];
#pragma unroll
            for (int wl = 0; wl < 8; ++wl)
                v[wl] = sp[(hl * 8 + wl) * PS + CV + c];
            float4 q0; q0.x = v[0]; q0.y = v[1]; q0.z = v[2]; q0.w = v[3];
            float4 q1; q1.x = v[4]; q1.y = v[5]; q1.z = v[6]; q1.w = v[7];
            float4* q = (float4*)(op + hl * WWD);
            q[0] = q0; q[1] = q1;
        }
    }
}

extern "C" void kernel_launch(void* const* d_in, const int* in_sizes, int n_in,
                              void* d_out, int out_size, void* d_ws, size_t ws_size,
                              hipStream_t stream) {
    (void)in_sizes; (void)n_in; (void)out_size; (void)ws_size;
    const float* x    = (const float*)d_in[0];
    const float* pan  = (const float*)d_in[1];
    const float* posi = (const float*)d_in[11];
    const float* posc = (const float*)d_in[12];
    unsigned short* wb = (unsigned short*)d_ws;  // 2*WTOT*2 = 98304 B of ws

    cvt_w<<<WTOT / 256, 256, 0, stream>>>(
        (const float*)d_in[2], (const float*)d_in[3], (const float*)d_in[4],
        (const float*)d_in[5], (const float*)d_in[6], (const float*)d_in[7],
        (const float*)d_in[8], (const float*)d_in[9], (const float*)d_in[10], wb);

    in2ma_main<<<4096, 256, 0, stream>>>(x, pan, posi, posc, wb, (float*)d_out);
}